// Round 8
// baseline (224.989 us; speedup 1.0000x reference)
//
#include <hip/hip_runtime.h>
#include <stdint.h>

typedef short short8 __attribute__((ext_vector_type(8)));
typedef float f32x4 __attribute__((ext_vector_type(4)));

#define B_    4
#define M_    2048
#define D_    1024
#define NH_   16
#define DH_   64
#define LOG2E 1.44269504f

#if __has_builtin(__builtin_amdgcn_exp2f)
#define EXP2F(x) __builtin_amdgcn_exp2f(x)
#else
#define EXP2F(x) exp2f(x)
#endif

__device__ __forceinline__ short f2bf(float f) {
  union { float f; uint32_t u; } v; v.f = f;
  uint32_t r = (v.u + 0x7fffu + ((v.u >> 16) & 1u)) >> 16;  // RNE
  return (short)r;
}

__device__ __forceinline__ void gl_lds16(const void* g, void* l) {
  __builtin_amdgcn_global_load_lds(
      (__attribute__((address_space(1))) void*)(g),
      (__attribute__((address_space(3))) void*)(l),
      16, 0, 0);
}

__device__ __forceinline__ f32x4 mfma16(short8 a, short8 b, f32x4 c) {
  return __builtin_amdgcn_mfma_f32_16x16x32_bf16(a, b, c, 0, 0, 0);
}

// counted waits (separate from barriers; barriers stay compiler-visible)
#define VM_WAIT(N)  asm volatile("s_waitcnt vmcnt(" #N ")" ::: "memory")
#define BAR_FENCE()                    \
  __builtin_amdgcn_s_barrier();        \
  __builtin_amdgcn_sched_barrier(0)

// ---------------- fp32 -> bf16 cast, all 5 tensors in one launch ----------------
__global__ __launch_bounds__(256) void cvt_all(const float* __restrict__ H,
                                               const float* __restrict__ s0,
                                               const float* __restrict__ s1,
                                               const float* __restrict__ s2,
                                               const float* __restrict__ s3,
                                               short* __restrict__ dH,
                                               short* __restrict__ d0,
                                               short* __restrict__ d1,
                                               short* __restrict__ d2,
                                               short* __restrict__ d3) {
  const int bidx = blockIdx.x;
  const float* src;
  short* dst;
  int i;
  if (bidx < 8192) {
    src = H; dst = dH; i = bidx * 256 + threadIdx.x;
  } else {
    const int y = (bidx - 8192) >> 10;
    src = (y == 0) ? s0 : (y == 1) ? s1 : (y == 2) ? s2 : s3;
    dst = (y == 0) ? d0 : (y == 1) ? d1 : (y == 2) ? d2 : d3;
    i = ((bidx - 8192) & 1023) * 256 + threadIdx.x;
  }
  float4 v = ((const float4*)src)[i];
  short4 o;
  o.x = f2bf(v.x); o.y = f2bf(v.y); o.z = f2bf(v.z); o.w = f2bf(v.w);
  ((short4*)dst)[i] = o;
}

// ---------------- QKV projection GEMM: R15 8-wave 256x128 4-phase/K-tile ----------------
// m201-class structure: BM=256 BN=128 BK=64(=2x32 half-steps), 512 threads
// (8 waves, 4M x 2N), z in grid (768 blocks = 3 exact CU-rounds). LDS 96KB:
// A half-subs 4x16KB + B half-subs 4x8KB, double-buffered at half-K grain.
// Per half-step phase: vmcnt(9)+bar+fence -> 8 ds_read_b128 -> 16 MFMA
// (setprio) -> bar -> issue 3 gl_lds for h+4 into the just-freed slot.
// Ledger: 3 loads/half-step x 4 in flight = 12; steady wait 9, peel 9/6/3/0.
// Chunk swizzle pair (acol/q4s) carried over -- rows == l>>2 (mod 16) so the
// same XOR applies on both sides (verified R8..R14 passes).
__global__ __launch_bounds__(512, 2) void gemm_qkv(const short* __restrict__ A,
                                                   const short* __restrict__ Wqb,
                                                   const short* __restrict__ Wkb,
                                                   const short* __restrict__ Wvb,
                                                   const float* __restrict__ bq,
                                                   const float* __restrict__ bk,
                                                   const float* __restrict__ bv,
                                                   short* __restrict__ Qo,
                                                   short* __restrict__ Ko,
                                                   short* __restrict__ Vo) {
  __shared__ char smem[98304];
  // A sub(i,s) at i*32768 + s*16384 (16KB: 256 rows x 32 shorts)
  // B sub(i,s) at 65536 + i*16384 + s*8192 (8KB: 128 rows x 32 shorts)

  const int L = blockIdx.x;            // 768
  const int xcd = L & 7;
  const int sL = L >> 3;               // 0..95
  const int m_local = sL & 3;
  const int nt = (sL >> 2) & 7;
  const int z = sL >> 5;               // 0,1,2
  const int m0 = (xcd * 4 + m_local) * 256;
  const int n0 = nt * 128;

  const short* Bz = (z == 0) ? Wqb : (z == 1) ? Wkb : Wvb;
  const float* bias = (z == 0) ? bq : (z == 1) ? bk : bv;

  const int tid = threadIdx.x;         // 0..511
  const int w = tid >> 6, l = tid & 63;
  const int q4 = l >> 4, c = l & 15;
  const int wr = w >> 1, wc = w & 1;   // wr 0..3 (M), wc 0..1 (N)

  f32x4 acc[4][4] = {};

  const int arow = (l >> 2);           // 0..15
  const int acol = ((l & 3) ^ ((l >> 3) & 3)) * 8;  // inverse-swizzled src col
  const int q4s = (q4 ^ ((c >> 1) & 3)) * 8;        // swizzled LDS read col

  // staging: per thread per half-step: 2 A-chunks + 1 B-chunk
  const size_t gA0 = (size_t)(m0 + w * 32 + arow) * 1024 + acol;
  const size_t gA1 = (size_t)(m0 + w * 32 + 16 + arow) * 1024 + acol;
  const size_t gB  = (size_t)(n0 + w * 16 + arow) * 1024 + acol;
  const int dA0 = (w * 128 + l) * 8;        // shorts within A-sub (8192)
  const int dA1 = (w * 128 + 64 + l) * 8;
  const int dB  = (w * 64 + l) * 8;         // shorts within B-sub (4096)

#define STAGE(I, S, H)                                                        \
  do {                                                                        \
    short* As_ = (short*)(smem + (I)*32768 + (S)*16384);                      \
    short* Bs_ = (short*)(smem + 65536 + (I)*16384 + (S)*8192);               \
    const size_t ko_ = (size_t)(H)*32;                                        \
    gl_lds16(A + gA0 + ko_, As_ + dA0);                                       \
    gl_lds16(A + gA1 + ko_, As_ + dA1);                                       \
    gl_lds16(Bz + gB + ko_, Bs_ + dB);                                        \
  } while (0)

#define PHASE(I, S, WAITN)                                                    \
  do {                                                                        \
    VM_WAIT(WAITN);                                                           \
    BAR_FENCE();                                                              \
    const short* As_ = (const short*)(smem + (I)*32768 + (S)*16384);          \
    const short* Bs_ = (const short*)(smem + 65536 + (I)*16384 + (S)*8192);   \
    short8 af[4], bfr[4];                                                     \
    _Pragma("unroll") for (int m = 0; m < 4; ++m)                             \
        af[m] = *(const short8*)(As_ + (wr * 64 + m * 16 + c) * 32 + q4s);    \
    _Pragma("unroll") for (int n = 0; n < 4; ++n)                             \
        bfr[n] = *(const short8*)(Bs_ + (wc * 64 + n * 16 + c) * 32 + q4s);   \
    __builtin_amdgcn_s_setprio(1);                                            \
    _Pragma("unroll") for (int m = 0; m < 4; ++m)                             \
        _Pragma("unroll") for (int n = 0; n < 4; ++n)                         \
            acc[m][n] = mfma16(af[m], bfr[n], acc[m][n]);                     \
    __builtin_amdgcn_s_setprio(0);                                            \
    BAR_FENCE();                                                              \
  } while (0)

  // prologue: half-steps 0..3 (FIFO: A,A,B per half-step) -> 12 in flight
  STAGE(0, 0, 0);
  STAGE(0, 1, 1);
  STAGE(1, 0, 2);
  STAGE(1, 1, 3);

  // steady: 28 phases; each issues h+4 right after its post-MFMA barrier
  for (int hh = 0; hh < 28; hh += 4) {
    PHASE(0, 0, 9); STAGE(0, 0, hh + 4);
    PHASE(0, 1, 9); STAGE(0, 1, hh + 5);
    PHASE(1, 0, 9); STAGE(1, 0, hh + 6);
    PHASE(1, 1, 9); STAGE(1, 1, hh + 7);
  }
  // peel: phases 28..31, drains 9/6/3/0
  PHASE(0, 0, 9);
  PHASE(0, 1, 6);
  PHASE(1, 0, 3);
  PHASE(1, 1, 0);

#undef STAGE
#undef PHASE

  __syncthreads();  // smem now reusable for epilogue

  if (z < 2) {
    // row-major epilogue: Cb[256][136] (69632 B)
    short* Cb = (short*)smem;
    short* outp = z ? Ko : Qo;
    const float scale = z ? 1.0f : (0.125f * LOG2E);  // Q pre-scaled for exp2-domain attn
#pragma unroll
    for (int n = 0; n < 4; ++n) {
      const float bvv = bias[n0 + wc * 64 + n * 16 + c];
#pragma unroll
      for (int m = 0; m < 4; ++m)
#pragma unroll
        for (int r = 0; r < 4; ++r)
          Cb[(wr * 64 + m * 16 + q4 * 4 + r) * 136 + wc * 64 + n * 16 + c] =
              f2bf((acc[m][n][r] + bvv) * scale);
    }
    __syncthreads();
#pragma unroll
    for (int p = 0; p < 8; ++p) {
      const int g = p * 512 + tid;
      const int row = g >> 4, seg = g & 15;
      *(short8*)(outp + (size_t)(m0 + row) * 1024 + n0 + seg * 8) =
          *(const short8*)(Cb + row * 136 + seg * 8);
    }
  } else {
    // V transposed epilogue: Cb[128 cols][264] (67584 B)
    short* Cb = (short*)smem;
#pragma unroll
    for (int n = 0; n < 4; ++n) {
      const float bvv = bias[n0 + wc * 64 + n * 16 + c];
#pragma unroll
      for (int m = 0; m < 4; ++m) {
        short4 pk;
        pk.x = f2bf(acc[m][n][0] + bvv);
        pk.y = f2bf(acc[m][n][1] + bvv);
        pk.z = f2bf(acc[m][n][2] + bvv);
        pk.w = f2bf(acc[m][n][3] + bvv);
        *(short4*)(Cb + (wc * 64 + n * 16 + c) * 264 + wr * 64 + m * 16 + q4 * 4) = pk;
      }
    }
    __syncthreads();
    const int bb = m0 >> 11;
    const int tokb = m0 & 2047;
#pragma unroll
    for (int p = 0; p < 8; ++p) {
      const int g = p * 512 + tid;
      const int col = g >> 5, rseg = g & 31;
      const int colg = n0 + col;
      const int hh2 = colg >> 6, dd = colg & 63;
      *(short8*)(Vo + ((size_t)(bb * NH_ + hh2) * DH_ + dd) * M_ + tokb + rseg * 8) =
          *(const short8*)(Cb + col * 264 + rseg * 8);
    }
  }
}

// ---------------- output projection GEMM (R13 128x128 structure, unchanged) ----------------
__global__ __launch_bounds__(256, 2) void gemm_oproj(const short* __restrict__ A,
                                                     const short* __restrict__ Bt,
                                                     const float* __restrict__ bias,
                                                     const int* __restrict__ pmask,
                                                     float* __restrict__ outp) {
  __shared__ char smem[33792];           // staging 32K; epilogue 64*132*4 = 33792
  short* Ab0 = (short*)smem;             // 128x32 (8 KB)
  short* Ab1 = (short*)(smem + 8192);
  short* Bb0 = (short*)(smem + 16384);   // 128x32 (8 KB)
  short* Bb1 = (short*)(smem + 24576);

  const int L = blockIdx.x + 8 * blockIdx.y;  // 512 blocks
  const int xcd = L & 7;
  const int s = L >> 3;        // 0..63
  const int m_local = s & 7;
  const int nt = s >> 3;       // 0..7
  const int m0 = (xcd * 8 + m_local) * 128;
  const int n0 = nt * 128;

  const int tid = threadIdx.x;
  const int w = tid >> 6, l = tid & 63;
  const int q4 = l >> 4, c = l & 15;
  const int wr = w >> 1, wc = w & 1;

  f32x4 acc[4][4] = {};
  const int arow = (l >> 2);
  const int acol = ((l & 3) ^ ((l >> 3) & 3)) * 8;   // inverse-swizzled source col
  const int q4s = (q4 ^ ((c >> 1) & 3)) * 8;         // swizzled LDS read offset

  // prologue: tile 0 -> buf0
#pragma unroll
  for (int st = 0; st < 2; ++st) {
    const int chunk = w * 2 + st;
    const size_t roff = (size_t)(chunk * 16 + arow) * 1024 + acol;
    gl_lds16(A + (size_t)m0 * 1024 + roff, Ab0 + chunk * 512);
    gl_lds16(Bt + (size_t)n0 * 1024 + roff, Bb0 + chunk * 512);
  }
  __syncthreads();

  for (int kk = 0; kk < 32; ++kk) {
    const int cur = kk & 1;
    if (kk + 1 < 32) {
      const int k0n = (kk + 1) * 32;
#pragma unroll
      for (int st = 0; st < 2; ++st) {
        const int chunk = w * 2 + st;
        const size_t roff = (size_t)(chunk * 16 + arow) * 1024 + k0n + acol;
        gl_lds16(A + (size_t)m0 * 1024 + roff, (cur ? Ab0 : Ab1) + chunk * 512);
        gl_lds16(Bt + (size_t)n0 * 1024 + roff, (cur ? Bb0 : Bb1) + chunk * 512);
      }
    }
    const short* Ab = cur ? Ab1 : Ab0;
    const short* Bb = cur ? Bb1 : Bb0;
    short8 af[4], bfr[4];
#pragma unroll
    for (int i = 0; i < 4; ++i)
      af[i] = *(const short8*)(Ab + (wr * 64 + i * 16 + c) * 32 + q4s);
#pragma unroll
    for (int j = 0; j < 4; ++j)
      bfr[j] = *(const short8*)(Bb + (wc * 64 + j * 16 + c) * 32 + q4s);
#pragma unroll
    for (int i = 0; i < 4; ++i)
#pragma unroll
      for (int j = 0; j < 4; ++j)
        acc[i][j] = mfma16(af[i], bfr[j], acc[i][j]);
    __syncthreads();
  }

  // fp32 epilogue: two 64-row halves through LDS [64][132], float4 stores
  float* Cf = (float*)smem;
#pragma unroll
  for (int half = 0; half < 2; ++half) {
    __syncthreads();
    if (wr == half) {
#pragma unroll
      for (int j = 0; j < 4; ++j) {
        const float bvv = bias[n0 + wc * 64 + j * 16 + c];
#pragma unroll
        for (int i = 0; i < 4; ++i)
#pragma unroll
          for (int r = 0; r < 4; ++r)
            Cf[(i * 16 + q4 * 4 + r) * 132 + wc * 64 + j * 16 + c] =
                acc[i][j][r] + bvv;
      }
    }
    __syncthreads();
#pragma unroll
    for (int p = 0; p < 8; ++p) {
      const int g = p * 256 + tid;
      const int row = g >> 5, seg = g & 31;
      const int rowg = m0 + half * 64 + row;
      const float mmv = (pmask[rowg] > 0) ? 1.0f : 0.0f;
      float4 v = *(const float4*)(Cf + row * 132 + seg * 4);
      v.x *= mmv; v.y *= mmv; v.z *= mmv; v.w *= mmv;
      *(float4*)(outp + (size_t)rowg * 1024 + n0 + seg * 4) = v;
    }
  }
}

// ---------------- windowed attention (R14 version, unchanged) ----------------
__global__ __launch_bounds__(256) void attn_kernel(const short* __restrict__ Qb,
                                                   const short* __restrict__ Kb,
                                                   const short* __restrict__ Vtb,
                                                   const int* __restrict__ pmask,
                                                   short* __restrict__ Attb) {
  __shared__ char smem[20480];
  short* Ks0 = (short*)smem;             // 32x64 (4 KB)
  short* Ks1 = (short*)(smem + 4096);
  short* Vs0 = (short*)(smem + 8192);    // 64x32 (4 KB)
  short* Vs1 = (short*)(smem + 12288);
  short* Ps  = (short*)(smem + 16384);   // 4 waves x 16x32 (4 KB)

  const int tid = threadIdx.x;
  const int w = tid >> 6, l = tid & 63;
  const int q4 = l >> 4, c = l & 15;
  const int qt = blockIdx.x, h = blockIdx.y, b = blockIdx.z;
  const short* Qrow = Qb + (size_t)(b * M_) * D_ + h * DH_;
  const short* Kbase = Kb + (size_t)(b * M_) * D_ + h * DH_;
  const short* Vbase = Vtb + (size_t)(b * NH_ + h) * DH_ * M_;
  const int* pm = pmask + b * M_;
  const int qrow0 = qt * 64 + w * 16;

  short8 aq0 = *(const short8*)(Qrow + (size_t)(qrow0 + c) * D_ + q4 * 8);
  short8 aq1 = *(const short8*)(Qrow + (size_t)(qrow0 + c) * D_ + 32 + q4 * 8);

  const int jt0 = max(0, 2 * qt - 2);
  const int jt1 = min(M_ / 32 - 1, 2 * qt + 3);

  const int kh = tid >> 7, krow = (tid >> 2) & 31, ch = tid & 3;
  const int vrow = tid >> 2;

  {
    const int j0 = jt0 * 32;
    gl_lds16(Kbase + (size_t)(j0 + krow) * D_ + kh * 32 + ch * 8, (char*)Ks0 + tid * 16);
    gl_lds16(Vbase + (size_t)vrow * M_ + j0 + ch * 8, (char*)Vs0 + tid * 16);
  }

  f32x4 o[4] = {};
  float lrun[4] = {0.f, 0.f, 0.f, 0.f};
  short* Pw = Ps + w * 512;
  const int ib = qrow0 + q4 * 4 - c;
  const float CLAMP = 28.0f * LOG2E;
  const float C16   = 16.0f * LOG2E;

  for (int jt = jt0; jt <= jt1; ++jt) {
    const int buf = (jt - jt0) & 1;
    const int j0 = jt * 32;
    if (jt < jt1) {
      const int j0n = j0 + 32;
      gl_lds16(Kbase + (size_t)(j0n + krow) * D_ + kh * 32 + ch * 8,
               (char*)(buf ? Ks0 : Ks1) + tid * 16);
      gl_lds16(Vbase + (size_t)vrow * M_ + j0n + ch * 8,
               (char*)(buf ? Vs0 : Vs1) + tid * 16);
      VM_WAIT(2);
    } else {
      VM_WAIT(0);
    }
    __builtin_amdgcn_sched_barrier(0);
    __builtin_amdgcn_s_barrier();
    __builtin_amdgcn_sched_barrier(0);

    const short* Kt = buf ? Ks1 : Ks0;
    const short* Vt = buf ? Vs1 : Vs0;
    short8 b00 = *(const short8*)(Kt + c * 32 + q4 * 8);
    short8 b10 = *(const short8*)(Kt + 1024 + c * 32 + q4 * 8);
    short8 b01 = *(const short8*)(Kt + (16 + c) * 32 + q4 * 8);
    short8 b11 = *(const short8*)(Kt + 1024 + (16 + c) * 32 + q4 * 8);
    f32x4 s0 = {}, s1 = {};
    __builtin_amdgcn_s_setprio(1);
    s0 = mfma16(aq0, b00, s0);
    s0 = mfma16(aq1, b10, s0);
    s1 = mfma16(aq0, b01, s1);
    s1 = mfma16(aq1, b11, s1);
    __builtin_amdgcn_s_setprio(0);

    const float w0m = (pm[j0 + c] > 0) ? 1.f : 0.f;
    const float w1m = (pm[j0 + 16 + c] > 0) ? 1.f : 0.f;
    const float eb = (float)(ib - j0) * LOG2E;

#pragma unroll
    for (int r = 0; r < 4; ++r) {
      const float er = eb + (float)r * LOG2E;
      const float d0 = fminf(fabsf(er), CLAMP);
      const float d1 = fminf(fabsf(er - C16), CLAMP);
      const float p0 = EXP2F(s0[r] - d0) * w0m;
      const float p1 = EXP2F(s1[r] - d1) * w1m;
      Pw[(q4 * 4 + r) * 32 + c] = f2bf(p0);
      Pw[(q4 * 4 + r) * 32 + 16 + c] = f2bf(p1);
      lrun[r] += p0 + p1;
    }
    short8 pa = *(const short8*)(Pw + c * 32 + q4 * 8);
    __builtin_amdgcn_s_setprio(1);
#pragma unroll
    for (int f = 0; f < 4; ++f) {
      short8 bv = *(const short8*)(Vt + (f * 16 + c) * 32 + q4 * 8);
      o[f] = mfma16(pa, bv, o[f]);
    }
    __builtin_amdgcn_s_setprio(0);
    __builtin_amdgcn_sched_barrier(0);
    __builtin_amdgcn_s_barrier();
  }

#pragma unroll
  for (int r = 0; r < 4; ++r) {
#pragma unroll
    for (int off = 1; off < 16; off <<= 1)
      lrun[r] += __shfl_xor(lrun[r], off);
  }

  short* Cb = (short*)smem;
#pragma unroll
  for (int r = 0; r < 4; ++r) {
    const float inv = 1.0f / lrun[r];
#pragma unroll
    for (int f = 0; f < 4; ++f)
      Cb[(w * 16 + q4 * 4 + r) * 72 + f * 16 + c] = f2bf(o[f][r] * inv);
  }
  __syncthreads();
#pragma unroll
  for (int p = 0; p < 2; ++p) {
    const int u = p * 256 + tid;
    const int row = u >> 3, seg = u & 7;
    *(short8*)(Attb + (size_t)(b * M_ + qt * 64 + row) * D_ + h * DH_ + seg * 8) =
        *(const short8*)(Cb + row * 72 + seg * 8);
  }
}

extern "C" void kernel_launch(void* const* d_in, const int* in_sizes, int n_in,
                              void* d_out, int out_size, void* d_ws, size_t ws_size,
                              hipStream_t stream) {
  const float* H     = (const float*)d_in[0];
  const int*   pmask = (const int*)d_in[1];
  const float* Wq    = (const float*)d_in[2];
  const float* bq    = (const float*)d_in[3];
  const float* Wk    = (const float*)d_in[4];
  const float* bk    = (const float*)d_in[5];
  const float* Wv    = (const float*)d_in[6];
  const float* bv    = (const float*)d_in[7];
  const float* Wo    = (const float*)d_in[8];
  const float* bo    = (const float*)d_in[9];
  float* out = (float*)d_out;
  char* ws = (char*)d_ws;

  short* Hb   = (short*)(ws);                  // 16 MB  (B*M x D bf16)
  short* Attb = (short*)(ws);                  // alias of Hb (dead after qkv)
  short* Wqb  = (short*)(ws + (16u << 20));
  short* Wkb  = (short*)(ws + (18u << 20));
  short* Wvb  = (short*)(ws + (20u << 20));
  short* Wob  = (short*)(ws + (22u << 20));
  short* Qb   = (short*)(ws + (24u << 20));    // 16 MB (B*M,1024), pre-scaled 0.125*log2e
  short* Kb2  = (short*)(ws + (40u << 20));    // 16 MB (B*M,1024)
  short* Vtb  = (short*)(ws + (56u << 20));    // 16 MB (B,NH,DH,M)

  cvt_all<<<8192 + 4096, 256, 0, stream>>>(H, Wq, Wk, Wv, Wo,
                                           Hb, Wqb, Wkb, Wvb, Wob);

  gemm_qkv<<<768, 512, 0, stream>>>(Hb, Wqb, Wkb, Wvb, bq, bk, bv,
                                    Qb, Kb2, Vtb);

  attn_kernel<<<dim3(M_ / 64, NH_, B_), 256, 0, stream>>>(Qb, Kb2, Vtb, pmask, Attb);

  gemm_oproj<<<dim3(8, 64), 256, 0, stream>>>(Attb, Wob, bo, pmask, out);
}

// Round 9
// 209.813 us; speedup vs baseline: 1.0723x; 1.0723x over previous
//
#include <hip/hip_runtime.h>
#include <stdint.h>

typedef short short8 __attribute__((ext_vector_type(8)));
typedef float f32x4 __attribute__((ext_vector_type(4)));

#define B_    4
#define M_    2048
#define D_    1024
#define NH_   16
#define DH_   64
#define LOG2E 1.44269504f

#if __has_builtin(__builtin_amdgcn_exp2f)
#define EXP2F(x) __builtin_amdgcn_exp2f(x)
#else
#define EXP2F(x) exp2f(x)
#endif

__device__ __forceinline__ short f2bf(float f) {
  union { float f; uint32_t u; } v; v.f = f;
  uint32_t r = (v.u + 0x7fffu + ((v.u >> 16) & 1u)) >> 16;  // RNE
  return (short)r;
}

__device__ __forceinline__ void gl_lds16(const void* g, void* l) {
  __builtin_amdgcn_global_load_lds(
      (__attribute__((address_space(1))) void*)(g),
      (__attribute__((address_space(3))) void*)(l),
      16, 0, 0);
}

__device__ __forceinline__ f32x4 mfma16(short8 a, short8 b, f32x4 c) {
  return __builtin_amdgcn_mfma_f32_16x16x32_bf16(a, b, c, 0, 0, 0);
}

// counted waits (separate from barriers; barriers stay compiler-visible)
#define VM_WAIT(N)  asm volatile("s_waitcnt vmcnt(" #N ")" ::: "memory")

// ---------------- fp32 -> bf16 cast, all 5 tensors in one launch ----------------
__global__ __launch_bounds__(256) void cvt_all(const float* __restrict__ H,
                                               const float* __restrict__ s0,
                                               const float* __restrict__ s1,
                                               const float* __restrict__ s2,
                                               const float* __restrict__ s3,
                                               short* __restrict__ dH,
                                               short* __restrict__ d0,
                                               short* __restrict__ d1,
                                               short* __restrict__ d2,
                                               short* __restrict__ d3) {
  const int bidx = blockIdx.x;
  const float* src;
  short* dst;
  int i;
  if (bidx < 8192) {
    src = H; dst = dH; i = bidx * 256 + threadIdx.x;
  } else {
    const int y = (bidx - 8192) >> 10;
    src = (y == 0) ? s0 : (y == 1) ? s1 : (y == 2) ? s2 : s3;
    dst = (y == 0) ? d0 : (y == 1) ? d1 : (y == 2) ? d2 : d3;
    i = ((bidx - 8192) & 1023) * 256 + threadIdx.x;
  }
  float4 v = ((const float4*)src)[i];
  short4 o;
  o.x = f2bf(v.x); o.y = f2bf(v.y); o.z = f2bf(v.z); o.w = f2bf(v.w);
  ((short4*)dst)[i] = o;
}

// ---------------- fused QKV projection GEMM (R8 structure -- measured best) ----------------
// Final: 55us = 937 TF effective = m97-structure plain-HIP ceiling (MfmaUtil
// ~39%). Bracketed by: 3-phase counted (55), 128x64 (61), no-LDS (spill,
// 220), 256x128 8-wave 4-phase (67). z-fusion (A staged once for Q,K,V;
// 48 MFMA/barrier) + both-sides chunk swizzle (bank-conflict 6.6M->0.33M)
// are the two proven wins. Q epilogue folds 0.125*log2e for exp2-domain attn.
__global__ __launch_bounds__(256, 2) void gemm_qkv(const short* __restrict__ A,
                                                   const short* __restrict__ Wqb,
                                                   const short* __restrict__ Wkb,
                                                   const short* __restrict__ Wvb,
                                                   const float* __restrict__ bq,
                                                   const float* __restrict__ bk,
                                                   const float* __restrict__ bv,
                                                   short* __restrict__ Qo,
                                                   short* __restrict__ Ko,
                                                   short* __restrict__ Vo) {
  __shared__ char smem_raw[65536];
  short* Ab0 = (short*)smem_raw;            // 128x32 (8 KB)
  short* Ab1 = (short*)(smem_raw + 8192);
  // B buffers: z in {0,1,2}, buf in {0,1}: smem + 16384 + z*16384 + buf*8192

  const int L = blockIdx.x + 8 * blockIdx.y;  // 512 blocks
  const int xcd = L & 7;
  const int s = L >> 3;        // 0..63
  const int m_local = s & 7;
  const int nt = s >> 3;       // 0..7
  const int m0 = (xcd * 8 + m_local) * 128;
  const int n0 = nt * 128;

  const int tid = threadIdx.x;
  const int w = tid >> 6, l = tid & 63;
  const int q4 = l >> 4, c = l & 15;
  const int wr = w >> 1, wc = w & 1;

  f32x4 acc[3][4][4] = {};
  const int arow = (l >> 2);
  // inverse-swizzled global source column (16B chunk permutation within 64B row)
  const int acol = ((l & 3) ^ ((l >> 3) & 3)) * 8;
  // swizzled LDS read offset (lane-constant across all fragment reads)
  const int q4s = (q4 ^ ((c >> 1) & 3)) * 8;

  const short* Bz0 = Wqb;
  const short* Bz1 = Wkb;
  const short* Bz2 = Wvb;

  // prologue: stage tile 0 -> buf0
#pragma unroll
  for (int st = 0; st < 2; ++st) {
    const int chunk = w * 2 + st;
    const size_t roff = (size_t)(chunk * 16 + arow) * 1024 + acol;
    gl_lds16(A + (size_t)m0 * 1024 + roff, Ab0 + chunk * 512);
    gl_lds16(Bz0 + (size_t)n0 * 1024 + roff, (short*)(smem_raw + 16384) + chunk * 512);
    gl_lds16(Bz1 + (size_t)n0 * 1024 + roff, (short*)(smem_raw + 32768) + chunk * 512);
    gl_lds16(Bz2 + (size_t)n0 * 1024 + roff, (short*)(smem_raw + 49152) + chunk * 512);
  }
  __syncthreads();

  for (int kk = 0; kk < 32; ++kk) {
    const int cur = kk & 1;
    if (kk + 1 < 32) {  // prefetch next K-tile into the other buffer
      const int k0n = (kk + 1) * 32;
#pragma unroll
      for (int st = 0; st < 2; ++st) {
        const int chunk = w * 2 + st;
        const size_t roff = (size_t)(chunk * 16 + arow) * 1024 + k0n + acol;
        gl_lds16(A + (size_t)m0 * 1024 + roff, (cur ? Ab0 : Ab1) + chunk * 512);
        gl_lds16(Bz0 + (size_t)n0 * 1024 + roff,
                 (short*)(smem_raw + 16384 + (cur ? 0 : 8192)) + chunk * 512);
        gl_lds16(Bz1 + (size_t)n0 * 1024 + roff,
                 (short*)(smem_raw + 32768 + (cur ? 0 : 8192)) + chunk * 512);
        gl_lds16(Bz2 + (size_t)n0 * 1024 + roff,
                 (short*)(smem_raw + 49152 + (cur ? 0 : 8192)) + chunk * 512);
      }
    }
    const short* Ab = cur ? Ab1 : Ab0;
    short8 af[4];
#pragma unroll
    for (int i = 0; i < 4; ++i)
      af[i] = *(const short8*)(Ab + (wr * 64 + i * 16 + c) * 32 + q4s);
#pragma unroll
    for (int z = 0; z < 3; ++z) {
      const short* Bb =
          (const short*)(smem_raw + 16384 + z * 16384 + (cur ? 8192 : 0));
      short8 bfr[4];
#pragma unroll
      for (int j = 0; j < 4; ++j)
        bfr[j] = *(const short8*)(Bb + (wc * 64 + j * 16 + c) * 32 + q4s);
#pragma unroll
      for (int i = 0; i < 4; ++i)
#pragma unroll
        for (int j = 0; j < 4; ++j)
          acc[z][i][j] = mfma16(af[i], bfr[j], acc[z][i][j]);
    }
    __syncthreads();  // drains prefetch (overlapped by the 48-MFMA compute)
  }

  // ---- epilogues: Q then K (row-major), then V (transposed), via Cb LDS ----
#pragma unroll
  for (int z = 0; z < 2; ++z) {
    short* Cb = (short*)smem_raw;
    const float* bias = z ? bk : bq;
    short* outp = z ? Ko : Qo;
    // Q is pre-scaled by 1/sqrt(dh) AND log2(e): attn softmax runs in exp2 domain
    const float scale = z ? 1.0f : (0.125f * LOG2E);
#pragma unroll
    for (int j = 0; j < 4; ++j) {
      const float bvv = bias[n0 + wc * 64 + j * 16 + c];
#pragma unroll
      for (int i = 0; i < 4; ++i)
#pragma unroll
        for (int r = 0; r < 4; ++r)
          Cb[(wr * 64 + i * 16 + q4 * 4 + r) * 136 + wc * 64 + j * 16 + c] =
              f2bf((acc[z][i][j][r] + bvv) * scale);
    }
    __syncthreads();
#pragma unroll
    for (int p = 0; p < 8; ++p) {
      const int g = p * 256 + tid;
      const int row = g >> 4, seg = g & 15;
      *(short8*)(outp + (size_t)(m0 + row) * 1024 + n0 + seg * 8) =
          *(const short8*)(Cb + row * 136 + seg * 8);
    }
    __syncthreads();
  }
  {
    short* Cb = (short*)smem_raw;
#pragma unroll
    for (int j = 0; j < 4; ++j) {
      const float bvv = bv[n0 + wc * 64 + j * 16 + c];
#pragma unroll
      for (int i = 0; i < 4; ++i) {
        short4 pk;
        pk.x = f2bf(acc[2][i][j][0] + bvv);
        pk.y = f2bf(acc[2][i][j][1] + bvv);
        pk.z = f2bf(acc[2][i][j][2] + bvv);
        pk.w = f2bf(acc[2][i][j][3] + bvv);
        *(short4*)(Cb + (wc * 64 + j * 16 + c) * 136 + wr * 64 + i * 16 + q4 * 4) = pk;
      }
    }
    __syncthreads();
    const int bb = m0 >> 11;
    const int tokb = m0 & 2047;
#pragma unroll
    for (int p = 0; p < 8; ++p) {
      const int g = p * 256 + tid;
      const int col = g >> 4, rseg = g & 15;
      const int colg = n0 + col;
      const int hh = colg >> 6, dd = colg & 63;
      *(short8*)(Vo + ((size_t)(bb * NH_ + hh) * DH_ + dd) * M_ + tokb + rseg * 8) =
          *(const short8*)(Cb + col * 136 + rseg * 8);
    }
  }
}

// ---------------- output projection GEMM (R13 128x128 structure) ----------------
__global__ __launch_bounds__(256, 2) void gemm_oproj(const short* __restrict__ A,
                                                     const short* __restrict__ Bt,
                                                     const float* __restrict__ bias,
                                                     const int* __restrict__ pmask,
                                                     float* __restrict__ outp) {
  __shared__ char smem[33792];           // staging 32K; epilogue 64*132*4 = 33792
  short* Ab0 = (short*)smem;             // 128x32 (8 KB)
  short* Ab1 = (short*)(smem + 8192);
  short* Bb0 = (short*)(smem + 16384);   // 128x32 (8 KB)
  short* Bb1 = (short*)(smem + 24576);

  const int L = blockIdx.x + 8 * blockIdx.y;  // 512 blocks
  const int xcd = L & 7;
  const int s = L >> 3;        // 0..63
  const int m_local = s & 7;
  const int nt = s >> 3;       // 0..7
  const int m0 = (xcd * 8 + m_local) * 128;
  const int n0 = nt * 128;

  const int tid = threadIdx.x;
  const int w = tid >> 6, l = tid & 63;
  const int q4 = l >> 4, c = l & 15;
  const int wr = w >> 1, wc = w & 1;

  f32x4 acc[4][4] = {};
  const int arow = (l >> 2);
  const int acol = ((l & 3) ^ ((l >> 3) & 3)) * 8;   // inverse-swizzled source col
  const int q4s = (q4 ^ ((c >> 1) & 3)) * 8;         // swizzled LDS read offset

  // prologue: tile 0 -> buf0
#pragma unroll
  for (int st = 0; st < 2; ++st) {
    const int chunk = w * 2 + st;
    const size_t roff = (size_t)(chunk * 16 + arow) * 1024 + acol;
    gl_lds16(A + (size_t)m0 * 1024 + roff, Ab0 + chunk * 512);
    gl_lds16(Bt + (size_t)n0 * 1024 + roff, Bb0 + chunk * 512);
  }
  __syncthreads();

  for (int kk = 0; kk < 32; ++kk) {
    const int cur = kk & 1;
    if (kk + 1 < 32) {
      const int k0n = (kk + 1) * 32;
#pragma unroll
      for (int st = 0; st < 2; ++st) {
        const int chunk = w * 2 + st;
        const size_t roff = (size_t)(chunk * 16 + arow) * 1024 + k0n + acol;
        gl_lds16(A + (size_t)m0 * 1024 + roff, (cur ? Ab0 : Ab1) + chunk * 512);
        gl_lds16(Bt + (size_t)n0 * 1024 + roff, (cur ? Bb0 : Bb1) + chunk * 512);
      }
    }
    const short* Ab = cur ? Ab1 : Ab0;
    const short* Bb = cur ? Bb1 : Bb0;
    short8 af[4], bfr[4];
#pragma unroll
    for (int i = 0; i < 4; ++i)
      af[i] = *(const short8*)(Ab + (wr * 64 + i * 16 + c) * 32 + q4s);
#pragma unroll
    for (int j = 0; j < 4; ++j)
      bfr[j] = *(const short8*)(Bb + (wc * 64 + j * 16 + c) * 32 + q4s);
#pragma unroll
    for (int i = 0; i < 4; ++i)
#pragma unroll
      for (int j = 0; j < 4; ++j)
        acc[i][j] = mfma16(af[i], bfr[j], acc[i][j]);
    __syncthreads();
  }

  // fp32 epilogue: two 64-row halves through LDS [64][132], float4 stores
  float* Cf = (float*)smem;
#pragma unroll
  for (int half = 0; half < 2; ++half) {
    __syncthreads();
    if (wr == half) {
#pragma unroll
      for (int j = 0; j < 4; ++j) {
        const float bvv = bias[n0 + wc * 64 + j * 16 + c];
#pragma unroll
        for (int i = 0; i < 4; ++i)
#pragma unroll
          for (int r = 0; r < 4; ++r)
            Cf[(i * 16 + q4 * 4 + r) * 132 + wc * 64 + j * 16 + c] =
                acc[i][j][r] + bvv;
      }
    }
    __syncthreads();
#pragma unroll
    for (int p = 0; p < 8; ++p) {
      const int g = p * 256 + tid;
      const int row = g >> 5, seg = g & 31;
      const int rowg = m0 + half * 64 + row;
      const float mmv = (pmask[rowg] > 0) ? 1.0f : 0.0f;
      float4 v = *(const float4*)(Cf + row * 132 + seg * 4);
      v.x *= mmv; v.y *= mmv; v.z *= mmv; v.w *= mmv;
      *(float4*)(outp + (size_t)rowg * 1024 + n0 + seg * 4) = v;
    }
  }
}

// ---------------- windowed attention (R14: exp2-domain + counted-vmcnt) ----------------
__global__ __launch_bounds__(256) void attn_kernel(const short* __restrict__ Qb,
                                                   const short* __restrict__ Kb,
                                                   const short* __restrict__ Vtb,
                                                   const int* __restrict__ pmask,
                                                   short* __restrict__ Attb) {
  __shared__ char smem[20480];
  short* Ks0 = (short*)smem;             // 32x64 (4 KB)
  short* Ks1 = (short*)(smem + 4096);
  short* Vs0 = (short*)(smem + 8192);    // 64x32 (4 KB)
  short* Vs1 = (short*)(smem + 12288);
  short* Ps  = (short*)(smem + 16384);   // 4 waves x 16x32 (4 KB)

  const int tid = threadIdx.x;
  const int w = tid >> 6, l = tid & 63;
  const int q4 = l >> 4, c = l & 15;
  const int qt = blockIdx.x, h = blockIdx.y, b = blockIdx.z;
  const short* Qrow = Qb + (size_t)(b * M_) * D_ + h * DH_;
  const short* Kbase = Kb + (size_t)(b * M_) * D_ + h * DH_;
  const short* Vbase = Vtb + (size_t)(b * NH_ + h) * DH_ * M_;
  const int* pm = pmask + b * M_;
  const int qrow0 = qt * 64 + w * 16;

  short8 aq0 = *(const short8*)(Qrow + (size_t)(qrow0 + c) * D_ + q4 * 8);
  short8 aq1 = *(const short8*)(Qrow + (size_t)(qrow0 + c) * D_ + 32 + q4 * 8);

  const int jt0 = max(0, 2 * qt - 2);
  const int jt1 = min(M_ / 32 - 1, 2 * qt + 3);

  const int kh = tid >> 7, krow = (tid >> 2) & 31, ch = tid & 3;
  const int vrow = tid >> 2;

  {
    const int j0 = jt0 * 32;
    gl_lds16(Kbase + (size_t)(j0 + krow) * D_ + kh * 32 + ch * 8, (char*)Ks0 + tid * 16);
    gl_lds16(Vbase + (size_t)vrow * M_ + j0 + ch * 8, (char*)Vs0 + tid * 16);
  }

  f32x4 o[4] = {};
  float lrun[4] = {0.f, 0.f, 0.f, 0.f};
  short* Pw = Ps + w * 512;
  const int ib = qrow0 + q4 * 4 - c;
  const float CLAMP = 28.0f * LOG2E;
  const float C16   = 16.0f * LOG2E;

  for (int jt = jt0; jt <= jt1; ++jt) {
    const int buf = (jt - jt0) & 1;
    const int j0 = jt * 32;
    if (jt < jt1) {
      const int j0n = j0 + 32;
      gl_lds16(Kbase + (size_t)(j0n + krow) * D_ + kh * 32 + ch * 8,
               (char*)(buf ? Ks0 : Ks1) + tid * 16);
      gl_lds16(Vbase + (size_t)vrow * M_ + j0n + ch * 8,
               (char*)(buf ? Vs0 : Vs1) + tid * 16);
      VM_WAIT(2);
    } else {
      VM_WAIT(0);
    }
    __builtin_amdgcn_sched_barrier(0);
    __builtin_amdgcn_s_barrier();
    __builtin_amdgcn_sched_barrier(0);

    const short* Kt = buf ? Ks1 : Ks0;
    const short* Vt = buf ? Vs1 : Vs0;
    short8 b00 = *(const short8*)(Kt + c * 32 + q4 * 8);
    short8 b10 = *(const short8*)(Kt + 1024 + c * 32 + q4 * 8);
    short8 b01 = *(const short8*)(Kt + (16 + c) * 32 + q4 * 8);
    short8 b11 = *(const short8*)(Kt + 1024 + (16 + c) * 32 + q4 * 8);
    f32x4 s0 = {}, s1 = {};
    __builtin_amdgcn_s_setprio(1);
    s0 = mfma16(aq0, b00, s0);
    s0 = mfma16(aq1, b10, s0);
    s1 = mfma16(aq0, b01, s1);
    s1 = mfma16(aq1, b11, s1);
    __builtin_amdgcn_s_setprio(0);

    const float w0m = (pm[j0 + c] > 0) ? 1.f : 0.f;
    const float w1m = (pm[j0 + 16 + c] > 0) ? 1.f : 0.f;
    const float eb = (float)(ib - j0) * LOG2E;

#pragma unroll
    for (int r = 0; r < 4; ++r) {
      const float er = eb + (float)r * LOG2E;
      const float d0 = fminf(fabsf(er), CLAMP);
      const float d1 = fminf(fabsf(er - C16), CLAMP);
      const float p0 = EXP2F(s0[r] - d0) * w0m;
      const float p1 = EXP2F(s1[r] - d1) * w1m;
      Pw[(q4 * 4 + r) * 32 + c] = f2bf(p0);
      Pw[(q4 * 4 + r) * 32 + 16 + c] = f2bf(p1);
      lrun[r] += p0 + p1;
    }
    short8 pa = *(const short8*)(Pw + c * 32 + q4 * 8);
    __builtin_amdgcn_s_setprio(1);
#pragma unroll
    for (int f = 0; f < 4; ++f) {
      short8 bv = *(const short8*)(Vt + (f * 16 + c) * 32 + q4 * 8);
      o[f] = mfma16(pa, bv, o[f]);
    }
    __builtin_amdgcn_s_setprio(0);
    __builtin_amdgcn_sched_barrier(0);
    __builtin_amdgcn_s_barrier();
  }

#pragma unroll
  for (int r = 0; r < 4; ++r) {
#pragma unroll
    for (int off = 1; off < 16; off <<= 1)
      lrun[r] += __shfl_xor(lrun[r], off);
  }

  short* Cb = (short*)smem;
#pragma unroll
  for (int r = 0; r < 4; ++r) {
    const float inv = 1.0f / lrun[r];
#pragma unroll
    for (int f = 0; f < 4; ++f)
      Cb[(w * 16 + q4 * 4 + r) * 72 + f * 16 + c] = f2bf(o[f][r] * inv);
  }
  __syncthreads();
#pragma unroll
  for (int p = 0; p < 2; ++p) {
    const int u = p * 256 + tid;
    const int row = u >> 3, seg = u & 7;
    *(short8*)(Attb + (size_t)(b * M_ + qt * 64 + row) * D_ + h * DH_ + seg * 8) =
        *(const short8*)(Cb + row * 72 + seg * 8);
  }
}

extern "C" void kernel_launch(void* const* d_in, const int* in_sizes, int n_in,
                              void* d_out, int out_size, void* d_ws, size_t ws_size,
                              hipStream_t stream) {
  const float* H     = (const float*)d_in[0];
  const int*   pmask = (const int*)d_in[1];
  const float* Wq    = (const float*)d_in[2];
  const float* bq    = (const float*)d_in[3];
  const float* Wk    = (const float*)d_in[4];
  const float* bk    = (const float*)d_in[5];
  const float* Wv    = (const float*)d_in[6];
  const float* bv    = (const float*)d_in[7];
  const float* Wo    = (const float*)d_in[8];
  const float* bo    = (const float*)d_in[9];
  float* out = (float*)d_out;
  char* ws = (char*)d_ws;

  short* Hb   = (short*)(ws);                  // 16 MB  (B*M x D bf16)
  short* Attb = (short*)(ws);                  // alias of Hb (dead after qkv)
  short* Wqb  = (short*)(ws + (16u << 20));
  short* Wkb  = (short*)(ws + (18u << 20));
  short* Wvb  = (short*)(ws + (20u << 20));
  short* Wob  = (short*)(ws + (22u << 20));
  short* Qb   = (short*)(ws + (24u << 20));    // 16 MB (B*M,1024), pre-scaled 0.125*log2e
  short* Kb2  = (short*)(ws + (40u << 20));    // 16 MB (B*M,1024)
  short* Vtb  = (short*)(ws + (56u << 20));    // 16 MB (B,NH,DH,M)

  cvt_all<<<8192 + 4096, 256, 0, stream>>>(H, Wq, Wk, Wv, Wo,
                                           Hb, Wqb, Wkb, Wvb, Wob);

  gemm_qkv<<<dim3(8, 64), 256, 0, stream>>>(Hb, Wqb, Wkb, Wvb, bq, bk, bv,
                                            Qb, Kb2, Vtb);

  attn_kernel<<<dim3(M_ / 64, NH_, B_), 256, 0, stream>>>(Qb, Kb2, Vtb, pmask, Attb);

  gemm_oproj<<<dim3(8, 64), 256, 0, stream>>>(Attb, Wob, bo, pmask, out);
}